// Round 17
// baseline (273.020 us; speedup 1.0000x reference)
//
#include <hip/hip_runtime.h>

#define CIN 128
#define COUT 128
#define NB_MAX 512          // max buckets (N<=131072 at 256 nodes/bucket)
#define BCAP 10240          // records per bucket; E[bucket]=8192, sd~91 -> 22-sigma margin
#define EPB 8192            // edges per partition block (1024 thr x 8)
#define AGG_D 4             // k_agg pipeline depth (batches of 8 edges in flight)

typedef float f32x4 __attribute__((ext_vector_type(4)));   // native vec (nontemporal + MFMA acc)
typedef short bf16x8 __attribute__((ext_vector_type(8)));  // MFMA A/B fragment (8 bf16)

__device__ __forceinline__ unsigned short f2bf(float x) {
    unsigned int b = __float_as_uint(x);
    b += 0x7FFFu + ((b >> 16) & 1u);           // round-to-nearest-even
    return (unsigned short)(b >> 16);
}
__device__ __forceinline__ float bf2f_hi(unsigned int u) {      // high half of dword
    return __uint_as_float(u & 0xFFFF0000u);
}
__device__ __forceinline__ float bf2f_lo(unsigned int u) {      // low half of dword
    return __uint_as_float(u << 16);
}

// ---------------- prep: zero bucket cursors + pack W into B-fragment layout ----------------
__global__ void k_prep(const float* __restrict__ W, unsigned short* __restrict__ WB,
                       int* __restrict__ cursor, int NB, int NBz) {
    int b = blockIdx.x;
    int t = threadIdx.x;
    if (b < NBz) {
        int i = b * 256 + t;
        if (i < NB) cursor[i] = 0;
    } else {
        int pos = (b - NBz) * 2048 + t * 8;
        int lane = (pos >> 3) & 63;
        int ks   = (pos >> 9) & 3;
        int ct   = pos >> 11;
        int k = ks * 32 + (lane >> 4) * 8;
        int c = ct * 16 + (lane & 15);
        #pragma unroll
        for (int j = 0; j < 8; ++j)
            WB[pos + j] = f2bf(W[(k + j) * COUT + c]);
    }
}

// ---------------- LDS-staged radix partition by dst>>8 (1024-thread blocks) ----------------
__global__ __launch_bounds__(1024) void k_part(const int* __restrict__ ei, const float* __restrict__ ew,
                                               int* __restrict__ cursor,
                                               unsigned long long* __restrict__ brec,
                                               int E, int NB) {
    __shared__ int hist[NB_MAX];
    __shared__ int base_[NB_MAX];
    int t = threadIdx.x;
    int chunk0 = blockIdx.x * EPB;
    bool vec_ok = ((E & 3) == 0);

    for (int i = t; i < NB; i += 1024) hist[i] = 0;
    __syncthreads();

    #pragma unroll
    for (int k = 0; k < EPB / 4096; ++k) {
        int e0 = chunk0 + (k * 1024 + t) * 4;
        if (vec_ok && e0 + 3 < E) {
            int4 d4 = *(const int4*)(ei + E + e0);
            atomicAdd(&hist[d4.x >> 8], 1);
            atomicAdd(&hist[d4.y >> 8], 1);
            atomicAdd(&hist[d4.z >> 8], 1);
            atomicAdd(&hist[d4.w >> 8], 1);
        } else {
            for (int q = 0; q < 4; ++q) {
                int e = e0 + q;
                if (e < E) atomicAdd(&hist[ei[E + e] >> 8], 1);
            }
        }
    }
    __syncthreads();

    for (int i = t; i < NB; i += 1024) {
        int c = hist[i];
        base_[i] = (c > 0) ? atomicAdd(&cursor[i], c) : 0;
        hist[i] = 0;
    }
    __syncthreads();

#define PLACE(ss, dd, ww) do {                                                    \
        int b_ = (dd) >> 8;                                                       \
        unsigned int q_ = (unsigned int)((ww) * 32767.0f + 0.5f);                 \
        int lp_ = atomicAdd(&hist[b_], 1);                                        \
        int pos_ = base_[b_] + lp_;                                               \
        if (pos_ < BCAP)                                                          \
            brec[(size_t)b_ * BCAP + pos_] =                                      \
                ((unsigned long long)((dd) & 255) << 32) |                        \
                (((unsigned int)(ss) << 15) | q_);                                \
    } while (0)

    #pragma unroll
    for (int k = 0; k < EPB / 4096; ++k) {
        int e0 = chunk0 + (k * 1024 + t) * 4;
        if (vec_ok && e0 + 3 < E) {
            int4 s4 = *(const int4*)(ei + e0);
            int4 d4 = *(const int4*)(ei + E + e0);
            float4 w4 = *(const float4*)(ew + e0);
            PLACE(s4.x, d4.x, w4.x);
            PLACE(s4.y, d4.y, w4.y);
            PLACE(s4.z, d4.z, w4.z);
            PLACE(s4.w, d4.w, w4.w);
        } else {
            for (int q = 0; q < 4; ++q) {
                int e = e0 + q;
                if (e < E) PLACE(ei[e], ei[E + e], ew[e]);
            }
        }
    }
#undef PLACE
}

// ---------------- per-bucket LDS counting sort -> exact CSR + dis ----------------
__global__ __launch_bounds__(256) void k_sortdeg(const unsigned long long* __restrict__ brec,
                                                 const int* __restrict__ cursor,
                                                 unsigned int* __restrict__ srec,
                                                 int2* __restrict__ rowinfo,
                                                 float* __restrict__ dis, int N) {
    __shared__ int histA[256];
    __shared__ int scanB[256];
    __shared__ int degq[256];
    __shared__ unsigned int stage[BCAP];   // 40 KB
    int t = threadIdx.x;
    int b = blockIdx.x;
    int cnt = min(cursor[b], BCAP);
    const unsigned long long* r = brec + (size_t)b * BCAP;

    histA[t] = 0; degq[t] = 0;
    __syncthreads();

    for (int j = t; j < cnt; j += 256) {
        unsigned long long v = r[j];
        int dl = (int)(v >> 32);
        atomicAdd(&histA[dl], 1);
        atomicAdd(&degq[dl], (int)((unsigned int)v & 0x7FFFu));
    }
    __syncthreads();

    int c = histA[t];
    scanB[t] = c;
    __syncthreads();
    #pragma unroll
    for (int off = 1; off < 256; off <<= 1) {
        int v = (t >= off) ? scanB[t - off] : 0;
        __syncthreads();
        scanB[t] += v;
        __syncthreads();
    }
    int excl = scanB[t] - c;

    int n = b * 256 + t;
    if (n < N) {
        dis[n] = rsqrtf(1.0f + (float)degq[t] * (1.0f / 32767.0f));
        rowinfo[n] = make_int2(b * BCAP + excl, c);
    }
    histA[t] = excl;
    __syncthreads();

    for (int j = t; j < cnt; j += 256) {
        unsigned long long v = r[j];
        int dl = (int)(v >> 32);
        int pos = atomicAdd(&histA[dl], 1);
        stage[pos] = (unsigned int)v;
    }
    __syncthreads();

    unsigned int* so = srec + (size_t)b * BCAP;
    for (int j = t; j < cnt; j += 256) so[j] = stage[j];
}

// ---------------- GEMM via MFMA: h'[n] = bf16( (X[n] @ W) * dis[n] ), 2 channel planes ----
__global__ __launch_bounds__(256) void k_gemm(const float* __restrict__ X,
                                              const unsigned short* __restrict__ WB,
                                              const float* __restrict__ dis,
                                              unsigned short* __restrict__ h, int N) {
    __shared__ unsigned short WBs[8 * 4 * 64 * 8];   // 32 KB
    __shared__ unsigned short outs[4][16 * 128];     // 16 KB (per-wave D staging)
    int t = threadIdx.x;
    int w = t >> 6, l = t & 63;
    int n0 = blockIdx.x * 64;

    {
        const uint4* src = (const uint4*)WB;
        uint4* dst = (uint4*)WBs;
        #pragma unroll
        for (int i = 0; i < 8; ++i) dst[t + i * 256] = src[t + i * 256];
    }

    int rowg = n0 + w * 16 + (l & 15);
    int rcl = min(rowg, N - 1);
    int kbase = (l >> 4) * 8;
    bf16x8 afrag[4];
    #pragma unroll
    for (int ks = 0; ks < 4; ++ks) {
        const float* xp = X + (size_t)rcl * CIN + ks * 32 + kbase;
        float4 x0 = *(const float4*)xp;
        float4 x1 = *(const float4*)(xp + 4);
        bf16x8 a;
        a[0] = (short)f2bf(x0.x); a[1] = (short)f2bf(x0.y);
        a[2] = (short)f2bf(x0.z); a[3] = (short)f2bf(x0.w);
        a[4] = (short)f2bf(x1.x); a[5] = (short)f2bf(x1.y);
        a[6] = (short)f2bf(x1.z); a[7] = (short)f2bf(x1.w);
        afrag[ks] = a;
    }

    __syncthreads();

    f32x4 acc[8];
    #pragma unroll
    for (int ct = 0; ct < 8; ++ct) acc[ct] = (f32x4){0.f, 0.f, 0.f, 0.f};

    const bf16x8* wb = (const bf16x8*)WBs;
    #pragma unroll
    for (int ct = 0; ct < 8; ++ct) {
        #pragma unroll
        for (int ks = 0; ks < 4; ++ks) {
            bf16x8 b = wb[(ct * 4 + ks) * 64 + l];
            acc[ct] = __builtin_amdgcn_mfma_f32_16x16x32_bf16(afrag[ks], b, acc[ct], 0, 0, 0);
        }
    }

    int rb = n0 + w * 16 + (l >> 4) * 4;
    float4 d4 = *(const float4*)(dis + rb);
    unsigned short* ow = &outs[w][0];
    #pragma unroll
    for (int ct = 0; ct < 8; ++ct) {
        int ocol = ct * 16 + (l & 15);
        int orow = (l >> 4) * 4;
        ow[(orow + 0) * 128 + ocol] = f2bf(acc[ct][0] * d4.x);
        ow[(orow + 1) * 128 + ocol] = f2bf(acc[ct][1] * d4.y);
        ow[(orow + 2) * 128 + ocol] = f2bf(acc[ct][2] * d4.z);
        ow[(orow + 3) * 128 + ocol] = f2bf(acc[ct][3] * d4.w);
    }

    size_t plane1 = (size_t)N * 64;
    #pragma unroll
    for (int i = 0; i < 4; ++i) {
        int off = i * 1024 + l * 16;
        int orow = off >> 8;
        int col = (off & 255) >> 1;
        int node = n0 + w * 16 + orow;
        if (node < N) {
            uint4 v = *(const uint4*)((const char*)ow + off);
            unsigned short* dst = h + (col < 64 ? 0 : plane1) + (size_t)node * 64 + (col & 63);
            *(uint4*)dst = v;
        }
    }
}

// ---------------- aggregation (one 64-channel plane per launch) ----------------
// 2 nodes/wave, 4 slots x 8 lanes (uint4) per node. Gathers land in a per-wave
// private LDS ring (AGG_D batches x 2 KB) via global_load_lds (per-lane global
// address, VGPR-free landing). Counted s_waitcnt vmcnt(12) keeps 4 batches
// (16 KB/wave issue window) in flight -> ~3x the VGPR-bound MLP.
__global__ __launch_bounds__(256) void k_agg(const unsigned short* __restrict__ h,
                                             const unsigned int* __restrict__ srec,
                                             const int2* __restrict__ rowinfo,
                                             const float* __restrict__ dis,
                                             const float* __restrict__ bias,
                                             float* __restrict__ out, int N, int plane) {
    __shared__ char gbuf[4][AGG_D][2048];   // 32 KB: per-wave gather landing ring
    int t = threadIdx.x;
    int wv   = t >> 6;
    int lane = t & 63;
    int grp  = lane >> 5;            // which node of the pair
    int l32  = lane & 31;
    int slot = l32 >> 3;             // edge slot 0..3
    int cl   = l32 & 7;              // 16B group within 128 B row
    int node = blockIdx.x * 8 + wv * 2 + grp;
    bool valid = node < N;
    int nodec = valid ? node : (N - 1);
    int2 ri = rowinfo[nodec];
    const unsigned int* r = srec + ri.x;
    int m = valid ? ri.y : 0;
    int mw = max(m, __shfl_xor(m, 32));                 // wave-uniform trip count
    const uint4* hu = (const uint4*)(h + (size_t)plane * N * 64);   // 8 uint4 per row
    char* mybuf = &gbuf[wv][0][0];

#define SB0() __builtin_amdgcn_sched_barrier(0)
#define LRS(d0, d1, basej) do {                                              \
        int j0_ = (basej) + slot;                                            \
        int j1_ = (basej) + 4 + slot;                                        \
        unsigned int q0_ = __builtin_nontemporal_load(r + j0_);              \
        unsigned int q1_ = __builtin_nontemporal_load(r + j1_);              \
        d0 = (j0_ < m) ? q0_ : 0u;                                           \
        d1 = (j1_ < m) ? q1_ : 0u;                                           \
    } while (0)
#define ISS(dbuf, r0v, r1v) do {                                                         \
        const uint4* g0_ = hu + (size_t)((r0v) >> 15) * 8 + cl;                          \
        const uint4* g1_ = hu + (size_t)((r1v) >> 15) * 8 + cl;                          \
        __builtin_amdgcn_global_load_lds(                                                \
            (__attribute__((address_space(1))) const void*)g0_,                         \
            (__attribute__((address_space(3))) void*)(dbuf), 16, 0, 0);                 \
        __builtin_amdgcn_global_load_lds(                                                \
            (__attribute__((address_space(1))) const void*)g1_,                         \
            (__attribute__((address_space(3))) void*)((dbuf) + 1024), 16, 0, 0);        \
    } while (0)
#define ACC2(r0v, r1v, v0, v1) do {                                                     \
        float w0_ = (float)((r0v) & 0x7FFFu) * (1.0f / 32767.0f);                       \
        float w1_ = (float)((r1v) & 0x7FFFu) * (1.0f / 32767.0f);                       \
        a[0] += w0_ * bf2f_lo(v0.x); a[1] += w0_ * bf2f_hi(v0.x);                       \
        a[2] += w0_ * bf2f_lo(v0.y); a[3] += w0_ * bf2f_hi(v0.y);                       \
        a[4] += w0_ * bf2f_lo(v0.z); a[5] += w0_ * bf2f_hi(v0.z);                       \
        a[6] += w0_ * bf2f_lo(v0.w); a[7] += w0_ * bf2f_hi(v0.w);                       \
        a[0] += w1_ * bf2f_lo(v1.x); a[1] += w1_ * bf2f_hi(v1.x);                       \
        a[2] += w1_ * bf2f_lo(v1.y); a[3] += w1_ * bf2f_hi(v1.y);                       \
        a[4] += w1_ * bf2f_lo(v1.z); a[5] += w1_ * bf2f_hi(v1.z);                       \
        a[6] += w1_ * bf2f_lo(v1.w); a[7] += w1_ * bf2f_hi(v1.w);                       \
    } while (0)

    // self-loop term (h' already carries dis[n]); 16/64 lanes active -> always issues
    float a[8] = {0.f, 0.f, 0.f, 0.f, 0.f, 0.f, 0.f, 0.f};
    if (slot == 0) {
        uint4 us = hu[(size_t)nodec * 8 + cl];
        if (valid) {
            a[0] = bf2f_lo(us.x); a[1] = bf2f_hi(us.x);
            a[2] = bf2f_lo(us.y); a[3] = bf2f_hi(us.y);
            a[4] = bf2f_lo(us.z); a[5] = bf2f_hi(us.z);
            a[6] = bf2f_lo(us.w); a[7] = bf2f_hi(us.w);
        }
    }
    SB0();

    // prologue: fill the 4-deep pipeline (order pinned by sched_barrier)
    unsigned int rA0, rA1, rB0, rB1, rC0, rC1, rD0, rD1, rE0, rE1;
    LRS(rA0, rA1, 0);  SB0(); ISS(mybuf + 0 * 2048, rA0, rA1); SB0();
    LRS(rB0, rB1, 8);  SB0(); ISS(mybuf + 1 * 2048, rB0, rB1); SB0();
    LRS(rC0, rC1, 16); SB0(); ISS(mybuf + 2 * 2048, rC0, rC1); SB0();
    LRS(rD0, rD1, 24); SB0(); ISS(mybuf + 3 * 2048, rD0, rD1); SB0();
    LRS(rE0, rE1, 32); SB0();

    for (int jb = 0; jb < mw; jb += 8) {
        char* slotbuf = mybuf + ((jb >> 3) & (AGG_D - 1)) * 2048;
        // batch jb's two gathers are the oldest 2 of <=16 outstanding vmem ops
        asm volatile("s_waitcnt vmcnt(12)" ::: "memory");
        SB0();
        uint4 v0 = *(const uint4*)(slotbuf + lane * 16);
        uint4 v1 = *(const uint4*)(slotbuf + 1024 + lane * 16);
        asm volatile("s_waitcnt lgkmcnt(0)" ::: "memory");   // reads done before slot reuse
        SB0();
        ACC2(rA0, rA1, v0, v1);
        SB0();
        ISS(slotbuf, rE0, rE1);        // issue batch jb+4*8 into the just-freed slot
        SB0();
        unsigned int t0, t1;
        LRS(t0, t1, jb + 40);          // records for batch jb+5*8
        SB0();
        rA0 = rB0; rA1 = rB1; rB0 = rC0; rB1 = rC1;
        rC0 = rD0; rC1 = rD1; rD0 = rE0; rD1 = rE1;
        rE0 = t0;  rE1 = t1;
    }
#undef SB0
#undef LRS
#undef ISS
#undef ACC2

    // combine the 4 edge slots within each 32-lane node group
    #pragma unroll
    for (int i = 0; i < 8; ++i) {
        a[i] += __shfl_xor(a[i], 8);
        a[i] += __shfl_xor(a[i], 16);
    }

    if (valid && slot == 0) {
        float dn = dis[node];
        int c0 = plane * 64 + cl * 8;
        float4 b0 = *(const float4*)(bias + c0);
        float4 b1 = *(const float4*)(bias + c0 + 4);
        f32x4 o0 = {a[0] * dn + b0.x, a[1] * dn + b0.y, a[2] * dn + b0.z, a[3] * dn + b0.w};
        f32x4 o1 = {a[4] * dn + b1.x, a[5] * dn + b1.y, a[6] * dn + b1.z, a[7] * dn + b1.w};
        f32x4* op = (f32x4*)(out + (size_t)node * COUT + c0);
        __builtin_nontemporal_store(o0, op);
        __builtin_nontemporal_store(o1, op + 1);
    }
}

// ---------------- launch ----------------
extern "C" void kernel_launch(void* const* d_in, const int* in_sizes, int n_in,
                              void* d_out, int out_size, void* d_ws, size_t ws_size,
                              hipStream_t stream) {
    const float* X    = (const float*)d_in[0];
    const int*   ei   = (const int*)d_in[1];
    const float* ew   = (const float*)d_in[2];
    const float* W    = (const float*)d_in[3];
    const float* bias = (const float*)d_in[4];
    float* out = (float*)d_out;

    int E = in_sizes[2];            // edge_weight count
    int N = out_size / COUT;        // B == 1
    int NB = (N + 255) >> 8;        // buckets of 256 nodes
    int NBz = (NB + 255) >> 8;      // cursor-zero blocks

    // workspace carve-up (~75 MB)
    char* ws = (char*)d_ws;
    unsigned short*     h    = (unsigned short*)ws;     ws += (size_t)N * COUT * 2;     // 25.6 MB (2 planes)
    unsigned long long* brec = (unsigned long long*)ws; ws += (size_t)NB * BCAP * 8;    // 32.0 MB
    unsigned int*       srec = (unsigned int*)ws;       ws += (size_t)NB * BCAP * 4;    // 16.0 MB
    int2*               rinf = (int2*)ws;               ws += (size_t)N * 8;            // 0.8 MB
    float*              dis  = (float*)ws;              ws += (size_t)(N + 64) * 4;     // +64 pad (gemm f4 reads)
    int*                cur  = (int*)ws;                ws += (size_t)NB * 4;
    unsigned short*     WB   = (unsigned short*)ws;     ws += 8 * 4 * 64 * 8 * 2;       // 32 KB

    k_prep   <<<NBz + 8, 256, 0, stream>>>(W, WB, cur, NB, NBz);
    k_part   <<<(E + EPB - 1) / EPB, 1024, 0, stream>>>(ei, ew, cur, brec, E, NB);
    k_sortdeg<<<NB, 256, 0, stream>>>(brec, cur, srec, rinf, dis, N);
    k_gemm   <<<(N + 63) / 64, 256, 0, stream>>>(X, WB, dis, h, N);
    k_agg    <<<(N + 7) / 8, 256, 0, stream>>>(h, srec, rinf, dis, bias, out, N, 0);
    k_agg    <<<(N + 7) / 8, 256, 0, stream>>>(h, srec, rinf, dis, bias, out, N, 1);
}

// Round 18
// 187.918 us; speedup vs baseline: 1.4529x; 1.4529x over previous
//
#include <hip/hip_runtime.h>

#define CIN 128
#define COUT 128
#define NB_MAX 512          // max buckets (N<=131072 at 256 nodes/bucket)
#define BCAP 10240          // records per bucket; E[bucket]=8192, sd~91 -> 22-sigma margin
#define EPB 8192            // edges per partition block (1024 thr x 8)

typedef float f32x4 __attribute__((ext_vector_type(4)));   // native vec (nontemporal + MFMA acc)
typedef short bf16x8 __attribute__((ext_vector_type(8)));  // MFMA A/B fragment (8 bf16)

__device__ __forceinline__ unsigned short f2bf(float x) {
    unsigned int b = __float_as_uint(x);
    b += 0x7FFFu + ((b >> 16) & 1u);           // round-to-nearest-even
    return (unsigned short)(b >> 16);
}
__device__ __forceinline__ float bf2f_hi(unsigned int u) {      // high half of dword
    return __uint_as_float(u & 0xFFFF0000u);
}
__device__ __forceinline__ float bf2f_lo(unsigned int u) {      // low half of dword
    return __uint_as_float(u << 16);
}

// ---------------- prep: zero bucket cursors + pack W into B-fragment layout ----------------
__global__ void k_prep(const float* __restrict__ W, unsigned short* __restrict__ WB,
                       int* __restrict__ cursor, int NB, int NBz) {
    int b = blockIdx.x;
    int t = threadIdx.x;
    if (b < NBz) {
        int i = b * 256 + t;
        if (i < NB) cursor[i] = 0;
    } else {
        int pos = (b - NBz) * 2048 + t * 8;
        int lane = (pos >> 3) & 63;
        int ks   = (pos >> 9) & 3;
        int ct   = pos >> 11;
        int k = ks * 32 + (lane >> 4) * 8;
        int c = ct * 16 + (lane & 15);
        #pragma unroll
        for (int j = 0; j < 8; ++j)
            WB[pos + j] = f2bf(W[(k + j) * COUT + c]);
    }
}

// ---------------- LDS-staged radix partition by dst>>8 (1024-thread blocks) ----------------
__global__ __launch_bounds__(1024) void k_part(const int* __restrict__ ei, const float* __restrict__ ew,
                                               int* __restrict__ cursor,
                                               unsigned long long* __restrict__ brec,
                                               int E, int NB) {
    __shared__ int hist[NB_MAX];
    __shared__ int base_[NB_MAX];
    int t = threadIdx.x;
    int chunk0 = blockIdx.x * EPB;
    bool vec_ok = ((E & 3) == 0);

    for (int i = t; i < NB; i += 1024) hist[i] = 0;
    __syncthreads();

    #pragma unroll
    for (int k = 0; k < EPB / 4096; ++k) {
        int e0 = chunk0 + (k * 1024 + t) * 4;
        if (vec_ok && e0 + 3 < E) {
            int4 d4 = *(const int4*)(ei + E + e0);
            atomicAdd(&hist[d4.x >> 8], 1);
            atomicAdd(&hist[d4.y >> 8], 1);
            atomicAdd(&hist[d4.z >> 8], 1);
            atomicAdd(&hist[d4.w >> 8], 1);
        } else {
            for (int q = 0; q < 4; ++q) {
                int e = e0 + q;
                if (e < E) atomicAdd(&hist[ei[E + e] >> 8], 1);
            }
        }
    }
    __syncthreads();

    for (int i = t; i < NB; i += 1024) {
        int c = hist[i];
        base_[i] = (c > 0) ? atomicAdd(&cursor[i], c) : 0;
        hist[i] = 0;
    }
    __syncthreads();

#define PLACE(ss, dd, ww) do {                                                    \
        int b_ = (dd) >> 8;                                                       \
        unsigned int q_ = (unsigned int)((ww) * 32767.0f + 0.5f);                 \
        int lp_ = atomicAdd(&hist[b_], 1);                                        \
        int pos_ = base_[b_] + lp_;                                               \
        if (pos_ < BCAP)                                                          \
            brec[(size_t)b_ * BCAP + pos_] =                                      \
                ((unsigned long long)((dd) & 255) << 32) |                        \
                (((unsigned int)(ss) << 15) | q_);                                \
    } while (0)

    #pragma unroll
    for (int k = 0; k < EPB / 4096; ++k) {
        int e0 = chunk0 + (k * 1024 + t) * 4;
        if (vec_ok && e0 + 3 < E) {
            int4 s4 = *(const int4*)(ei + e0);
            int4 d4 = *(const int4*)(ei + E + e0);
            float4 w4 = *(const float4*)(ew + e0);
            PLACE(s4.x, d4.x, w4.x);
            PLACE(s4.y, d4.y, w4.y);
            PLACE(s4.z, d4.z, w4.z);
            PLACE(s4.w, d4.w, w4.w);
        } else {
            for (int q = 0; q < 4; ++q) {
                int e = e0 + q;
                if (e < E) PLACE(ei[e], ei[E + e], ew[e]);
            }
        }
    }
#undef PLACE
}

// ---------------- per-bucket LDS counting sort -> exact CSR + dis ----------------
__global__ __launch_bounds__(256) void k_sortdeg(const unsigned long long* __restrict__ brec,
                                                 const int* __restrict__ cursor,
                                                 unsigned int* __restrict__ srec,
                                                 int2* __restrict__ rowinfo,
                                                 float* __restrict__ dis, int N) {
    __shared__ int histA[256];
    __shared__ int scanB[256];
    __shared__ int degq[256];
    __shared__ unsigned int stage[BCAP];   // 40 KB
    int t = threadIdx.x;
    int b = blockIdx.x;
    int cnt = min(cursor[b], BCAP);
    const unsigned long long* r = brec + (size_t)b * BCAP;

    histA[t] = 0; degq[t] = 0;
    __syncthreads();

    for (int j = t; j < cnt; j += 256) {
        unsigned long long v = r[j];
        int dl = (int)(v >> 32);
        atomicAdd(&histA[dl], 1);
        atomicAdd(&degq[dl], (int)((unsigned int)v & 0x7FFFu));
    }
    __syncthreads();

    int c = histA[t];
    scanB[t] = c;
    __syncthreads();
    #pragma unroll
    for (int off = 1; off < 256; off <<= 1) {
        int v = (t >= off) ? scanB[t - off] : 0;
        __syncthreads();
        scanB[t] += v;
        __syncthreads();
    }
    int excl = scanB[t] - c;

    int n = b * 256 + t;
    if (n < N) {
        dis[n] = rsqrtf(1.0f + (float)degq[t] * (1.0f / 32767.0f));
        rowinfo[n] = make_int2(b * BCAP + excl, c);
    }
    histA[t] = excl;
    __syncthreads();

    for (int j = t; j < cnt; j += 256) {
        unsigned long long v = r[j];
        int dl = (int)(v >> 32);
        int pos = atomicAdd(&histA[dl], 1);
        stage[pos] = (unsigned int)v;
    }
    __syncthreads();

    unsigned int* so = srec + (size_t)b * BCAP;
    for (int j = t; j < cnt; j += 256) so[j] = stage[j];
}

// ---------------- GEMM via MFMA: h'[n] = bf16( (X[n] @ W) * dis[n] ), [N][128] layout ----
__global__ __launch_bounds__(256) void k_gemm(const float* __restrict__ X,
                                              const unsigned short* __restrict__ WB,
                                              const float* __restrict__ dis,
                                              unsigned short* __restrict__ h, int N) {
    __shared__ unsigned short WBs[8 * 4 * 64 * 8];   // 32 KB
    __shared__ unsigned short outs[4][16 * 128];     // 16 KB (per-wave D staging)
    int t = threadIdx.x;
    int w = t >> 6, l = t & 63;
    int n0 = blockIdx.x * 64;

    {
        const uint4* src = (const uint4*)WB;
        uint4* dst = (uint4*)WBs;
        #pragma unroll
        for (int i = 0; i < 8; ++i) dst[t + i * 256] = src[t + i * 256];
    }

    // A fragments: lane l covers row n0+w*16+(l&15), k = ks*32 + (l>>4)*8 + 0..7
    int rowg = n0 + w * 16 + (l & 15);
    int rcl = min(rowg, N - 1);
    int kbase = (l >> 4) * 8;
    bf16x8 afrag[4];
    #pragma unroll
    for (int ks = 0; ks < 4; ++ks) {
        const float* xp = X + (size_t)rcl * CIN + ks * 32 + kbase;
        float4 x0 = __builtin_nontemporal_load((const f32x4*)xp)
                        [0] == 0.f ? *(const float4*)xp : *(const float4*)xp;  // (kept simple below)
        (void)x0;
        float4 xa = *(const float4*)xp;
        float4 xb = *(const float4*)(xp + 4);
        bf16x8 a;
        a[0] = (short)f2bf(xa.x); a[1] = (short)f2bf(xa.y);
        a[2] = (short)f2bf(xa.z); a[3] = (short)f2bf(xa.w);
        a[4] = (short)f2bf(xb.x); a[5] = (short)f2bf(xb.y);
        a[6] = (short)f2bf(xb.z); a[7] = (short)f2bf(xb.w);
        afrag[ks] = a;
    }

    __syncthreads();   // WBs ready

    f32x4 acc[8];
    #pragma unroll
    for (int ct = 0; ct < 8; ++ct) acc[ct] = (f32x4){0.f, 0.f, 0.f, 0.f};

    const bf16x8* wb = (const bf16x8*)WBs;   // index (ct*4+ks)*64 + l
    #pragma unroll
    for (int ct = 0; ct < 8; ++ct) {
        #pragma unroll
        for (int ks = 0; ks < 4; ++ks) {
            bf16x8 b = wb[(ct * 4 + ks) * 64 + l];
            acc[ct] = __builtin_amdgcn_mfma_f32_16x16x32_bf16(afrag[ks], b, acc[ct], 0, 0, 0);
        }
    }

    // D layout: lane l, reg r -> row (l>>4)*4+r, col l&15 (m89-verified).
    int rb = n0 + w * 16 + (l >> 4) * 4;             // dis padded by 64 floats -> safe
    float4 d4 = *(const float4*)(dis + rb);
    unsigned short* ow = &outs[w][0];
    #pragma unroll
    for (int ct = 0; ct < 8; ++ct) {
        int ocol = ct * 16 + (l & 15);
        int orow = (l >> 4) * 4;
        ow[(orow + 0) * 128 + ocol] = f2bf(acc[ct][0] * d4.x);
        ow[(orow + 1) * 128 + ocol] = f2bf(acc[ct][1] * d4.y);
        ow[(orow + 2) * 128 + ocol] = f2bf(acc[ct][2] * d4.z);
        ow[(orow + 3) * 128 + ocol] = f2bf(acc[ct][3] * d4.w);
    }

    // store full 256B rows to h[N][128]
    #pragma unroll
    for (int i = 0; i < 4; ++i) {
        int off = i * 1024 + l * 16;                 // byte offset in wave's 4KB tile
        int orow = off >> 8;
        int col = (off & 255) >> 1;                  // 0..127, multiples of 8
        int node = n0 + w * 16 + orow;
        if (node < N) {
            uint4 v = *(const uint4*)((const char*)ow + off);
            *(uint4*)(h + (size_t)node * COUT + col) = v;
        }
    }
}

// ---------------- aggregation: out[n] = dis[n]*(h'[n] + sum ew*h'[src]) + b ----------------
// Single pass over full 256B rows. 2 nodes per wave; 16 lanes per edge (uint4 =
// 8 bf16 channels per lane); one gather instr covers 4 edges; records
// prefetched one batch ahead (nontemporal: read-once, keep L2 for h').
__global__ __launch_bounds__(256) void k_agg(const unsigned short* __restrict__ h,
                                             const unsigned int* __restrict__ srec,
                                             const int2* __restrict__ rowinfo,
                                             const float* __restrict__ dis,
                                             const float* __restrict__ bias,
                                             float* __restrict__ out, int N) {
    int wave = threadIdx.x >> 6;
    int lane = threadIdx.x & 63;
    int slot = lane >> 4;            // 0..3: {nodeA,e0},{nodeA,e1},{nodeB,e0},{nodeB,e1}
    int sl   = slot & 1;             // edge parity within node
    int cl   = lane & 15;            // 16B group within 256B row (8 bf16 channels)
    int node = blockIdx.x * 8 + wave * 2 + (slot >> 1);
    bool valid = node < N;
    int2 ri = valid ? rowinfo[node] : make_int2(0, 0);
    const unsigned int* r = srec + ri.x;
    int m = ri.y;
    const uint4* hu = (const uint4*)h;   // 16 uint4 per 128-channel row

    float a[8] = {0.f, 0.f, 0.f, 0.f, 0.f, 0.f, 0.f, 0.f};
    if (valid && sl == 0) {              // self-loop term (h' already carries dis[n])
        uint4 us = hu[(size_t)node * 16 + cl];
        a[0] = bf2f_lo(us.x); a[1] = bf2f_hi(us.x);
        a[2] = bf2f_lo(us.y); a[3] = bf2f_hi(us.y);
        a[4] = bf2f_lo(us.z); a[5] = bf2f_hi(us.z);
        a[6] = bf2f_lo(us.w); a[7] = bf2f_hi(us.w);
    }

#define LOAD_REC(dst, base_j) do {                                           \
        _Pragma("unroll")                                                    \
        for (int u = 0; u < 4; ++u) {                                        \
            int j_ = (base_j) + u * 2 + sl;                                  \
            unsigned int q_ = 0u;                                            \
            if (j_ < m) q_ = __builtin_nontemporal_load(r + j_);             \
            dst[u] = q_;                                                     \
        } } while (0)

    unsigned int rrc[4];
    LOAD_REC(rrc, 0);
    for (int j0 = 0; j0 < m; j0 += 8) {
        unsigned int rrn[4];
        LOAD_REC(rrn, j0 + 8);               // prefetch next batch's records
        #pragma unroll
        for (int u = 0; u < 4; ++u) {        // gather + accumulate current batch
            unsigned int rr = rrc[u];
            float w = (float)(rr & 0x7FFFu) * (1.0f / 32767.0f);
            uint4 v = hu[(size_t)(rr >> 15) * 16 + cl];
            a[0] += w * bf2f_lo(v.x); a[1] += w * bf2f_hi(v.x);
            a[2] += w * bf2f_lo(v.y); a[3] += w * bf2f_hi(v.y);
            a[4] += w * bf2f_lo(v.z); a[5] += w * bf2f_hi(v.z);
            a[6] += w * bf2f_lo(v.w); a[7] += w * bf2f_hi(v.w);
        }
        #pragma unroll
        for (int u = 0; u < 4; ++u) rrc[u] = rrn[u];
    }
#undef LOAD_REC

    #pragma unroll
    for (int i = 0; i < 8; ++i) a[i] += __shfl_xor(a[i], 16);   // combine edge-parity pair

    if (valid && sl == 0) {
        float dn = dis[node];
        int c0 = cl * 8;
        float4 b0 = *(const float4*)(bias + c0);
        float4 b1 = *(const float4*)(bias + c0 + 4);
        f32x4 o0 = {a[0] * dn + b0.x, a[1] * dn + b0.y, a[2] * dn + b0.z, a[3] * dn + b0.w};
        f32x4 o1 = {a[4] * dn + b1.x, a[5] * dn + b1.y, a[6] * dn + b1.z, a[7] * dn + b1.w};
        f32x4* op = (f32x4*)(out + (size_t)node * COUT + c0);
        __builtin_nontemporal_store(o0, op);        // write-once: keep out of L2
        __builtin_nontemporal_store(o1, op + 1);
    }
}

// ---------------- launch ----------------
extern "C" void kernel_launch(void* const* d_in, const int* in_sizes, int n_in,
                              void* d_out, int out_size, void* d_ws, size_t ws_size,
                              hipStream_t stream) {
    const float* X    = (const float*)d_in[0];
    const int*   ei   = (const int*)d_in[1];
    const float* ew   = (const float*)d_in[2];
    const float* W    = (const float*)d_in[3];
    const float* bias = (const float*)d_in[4];
    float* out = (float*)d_out;

    int E = in_sizes[2];            // edge_weight count
    int N = out_size / COUT;        // B == 1
    int NB = (N + 255) >> 8;        // buckets of 256 nodes
    int NBz = (NB + 255) >> 8;      // cursor-zero blocks

    // workspace carve-up (~75 MB)
    char* ws = (char*)d_ws;
    unsigned short*     h    = (unsigned short*)ws;     ws += (size_t)N * COUT * 2;     // 25.6 MB
    unsigned long long* brec = (unsigned long long*)ws; ws += (size_t)NB * BCAP * 8;    // 32.0 MB
    unsigned int*       srec = (unsigned int*)ws;       ws += (size_t)NB * BCAP * 4;    // 16.0 MB
    int2*               rinf = (int2*)ws;               ws += (size_t)N * 8;            // 0.8 MB
    float*              dis  = (float*)ws;              ws += (size_t)(N + 64) * 4;     // +64 pad (gemm f4 reads)
    int*                cur  = (int*)ws;                ws += (size_t)NB * 4;
    unsigned short*     WB   = (unsigned short*)ws;     ws += 8 * 4 * 64 * 8 * 2;       // 32 KB

    k_prep   <<<NBz + 8, 256, 0, stream>>>(W, WB, cur, NB, NBz);
    k_part   <<<(E + EPB - 1) / EPB, 1024, 0, stream>>>(ei, ew, cur, brec, E, NB);
    k_sortdeg<<<NB, 256, 0, stream>>>(brec, cur, srec, rinf, dis, N);
    k_gemm   <<<(N + 63) / 64, 256, 0, stream>>>(X, WB, dis, h, N);
    k_agg    <<<(N + 7) / 8, 256, 0, stream>>>(h, srec, rinf, dis, bias, out, N);
}